// Round 6
// baseline (1217.874 us; speedup 1.0000x reference)
//
#include <hip/hip_runtime.h>
#include <math.h>

// Problem constants
constexpr int NN   = 50000;          // nodes
constexpr int NE   = 800000;         // edges (without self loops)
constexpr int EP   = NE + NN;        // edges + self loops = 850000
constexpr int FIN  = 500;
constexpr int C    = 128;
constexpr int NCLS = 7;
constexpr int NL   = 8;
constexpr float ALPHA = 0.1f;
constexpr float NEG_SLOPE = 0.2f;

typedef __bf16 bf16;
typedef __bf16 bf16x8 __attribute__((ext_vector_type(8)));
typedef float  f32x4  __attribute__((ext_vector_type(4)));

__device__ inline unsigned short f2bu(float f) {
    bf16 b = (bf16)f;
    return __builtin_bit_cast(unsigned short, b);
}
__device__ inline float bulo(unsigned u) { return __builtin_bit_cast(float, u << 16); }
__device__ inline float buhi(unsigned u) { return __builtin_bit_cast(float, u & 0xffff0000u); }

// ---------------- graph prep ----------------
__global__ void count_deg_k(const int* __restrict__ dst, int* __restrict__ deg, int e) {
    int i = blockIdx.x * blockDim.x + threadIdx.x;
    if (i < e) atomicAdd(&deg[dst[i]], 1);
}

// ---- 3-pass scan (deg+1 for self loop; also emits dinv) ----
constexpr int SCB = 256;
constexpr int NSB = (NN + SCB - 1) / SCB;      // 196

__global__ __launch_bounds__(SCB) void scan1_k(const int* __restrict__ deg,
                                               int* __restrict__ exoff,
                                               int* __restrict__ bsum,
                                               float* __restrict__ dinv, int n) {
    __shared__ int s[SCB];
    int t = threadIdx.x;
    int i = blockIdx.x * SCB + t;
    int v = (i < n) ? deg[i] + 1 : 0;          // +1: self loop
    if (i < n) dinv[i] = rsqrtf((float)v);
    s[t] = v;
    __syncthreads();
    for (int off = 1; off < SCB; off <<= 1) {
        int u = (t >= off) ? s[t - off] : 0;
        __syncthreads();
        s[t] += u;
        __syncthreads();
    }
    if (i < n) exoff[i] = s[t] - v;
    if (t == SCB - 1) bsum[blockIdx.x] = s[t];
}

__global__ __launch_bounds__(SCB) void scan2_k(const int* __restrict__ bsum,
                                               int* __restrict__ boff, int nb) {
    __shared__ int s[SCB];
    int t = threadIdx.x;
    int v = (t < nb) ? bsum[t] : 0;
    s[t] = v;
    __syncthreads();
    for (int off = 1; off < SCB; off <<= 1) {
        int u = (t >= off) ? s[t - off] : 0;
        __syncthreads();
        s[t] += u;
        __syncthreads();
    }
    if (t < nb) boff[t] = s[t] - v;
}

__global__ __launch_bounds__(SCB) void scan3_k(const int* __restrict__ exoff,
                                               const int* __restrict__ boff,
                                               int* __restrict__ offs,
                                               int* __restrict__ cursor, int n) {
    int i = blockIdx.x * SCB + threadIdx.x;
    if (i < n) {
        int o = exoff[i] + boff[blockIdx.x];
        offs[i] = o;
        cursor[i] = o;
    }
    if (i == 0) offs[n] = EP;
}

// csr fill: scatter {src, ew} as one int2 record
__global__ void csr_fill_k(const int* __restrict__ src, const int* __restrict__ dst,
                           const float* __restrict__ dinv, int* __restrict__ cursor,
                           int2* __restrict__ csr2) {
    int e = blockIdx.x * blockDim.x + threadIdx.x;
    if (e >= EP) return;
    int s, d;
    if (e < NE) { s = src[e]; d = dst[e]; }
    else { s = d = e - NE; }
    float ew = dinv[s] * dinv[d];
    int pos = atomicAdd(&cursor[d], 1);
    csr2[pos] = make_int2(s, __builtin_bit_cast(int, ew));
}

// alp[l] = lin_w[l] @ att_l[l]; arp[l] = lin_w[l] @ att_r[l]  (fp32)
__global__ void attproj_k(const float* __restrict__ lin_w, const float* __restrict__ att_l,
                          const float* __restrict__ att_r, float* __restrict__ alp,
                          float* __restrict__ arp) {
    __shared__ float al[C], ar[C];
    int l = blockIdx.x;
    int k = threadIdx.x;
    al[k] = att_l[l * C + k];
    ar[k] = att_r[l * C + k];
    __syncthreads();
    const float* w = lin_w + (size_t)l * C * C + (size_t)k * C;
    float s1 = 0.f, s2 = 0.f;
    #pragma unroll 8
    for (int c = 0; c < C; ++c) { float v = w[c]; s1 += v * al[c]; s2 += v * ar[c]; }
    alp[l * C + k] = s1;
    arp[l * C + k] = s2;
}

// ---------------- merged weight pre-pack (MFMA B-fragment layout) ----------------
// blocks [0, NL*64)            : wpn   (l = b/64; inner nt*4+kb, NT=16, KB=4)
// blocks [NL*64, NL*96)        : w1    (l = (b-NL*64)/32; NT=8, KB=4)
// blocks [NL*96, NL*96 + 128)  : lin0  (NT=8, KB=16, K zero-padded to 512)
__global__ void pack_k(const float* __restrict__ w_p, const float* __restrict__ w_n,
                       const float* __restrict__ w1, const float* __restrict__ lin0_w,
                       bf16* __restrict__ wpnt, bf16* __restrict__ w1t,
                       bf16* __restrict__ lin0t) {
    int b = blockIdx.x;
    int lane = threadIdx.x;
    if (b < NL * 64) {
        int l = b >> 6, inner = b & 63;
        int nt = inner >> 2, kb = inner & 3;
        const float* W = ((nt < 8) ? w_p : w_n) + (size_t)l * C * C;
        int col = (nt & 7) * 16 + (lane & 15);
        int k0 = kb * 32 + (lane >> 4) * 8;
        bf16* o = wpnt + (((size_t)l * 64 + inner) * 64 + lane) * 8;
        #pragma unroll
        for (int j = 0; j < 8; ++j) o[j] = (bf16)W[(size_t)(k0 + j) * C + col];
    } else if (b < NL * 96) {
        int idx = b - NL * 64;
        int l = idx >> 5, inner = idx & 31;
        int nt = inner >> 2, kb = inner & 3;
        const float* W = w1 + (size_t)l * C * C;
        int col = nt * 16 + (lane & 15);
        int k0 = kb * 32 + (lane >> 4) * 8;
        bf16* o = w1t + (((size_t)l * 32 + inner) * 64 + lane) * 8;
        #pragma unroll
        for (int j = 0; j < 8; ++j) o[j] = (bf16)W[(size_t)(k0 + j) * C + col];
    } else {
        int idx = b - NL * 96;
        int nt = idx >> 4, kb = idx & 15;
        int col = nt * 16 + (lane & 15);
        int k0 = kb * 32 + (lane >> 4) * 8;
        bf16* o = lin0t + (((size_t)(nt * 16 + kb)) * 64 + lane) * 8;
        #pragma unroll
        for (int j = 0; j < 8; ++j) {
            int k = k0 + j;
            o[j] = (bf16)((k < FIN) ? lin0_w[(size_t)k * C + col] : 0.f);
        }
    }
}

// x [N,500] fp32 -> xb [N,512] bf16 (zero-padded), 8 cols/thread, 16B stores
__global__ __launch_bounds__(256) void conv_x_k(const float* __restrict__ x,
                                                unsigned* __restrict__ xb_u) {
    int gid = blockIdx.x * blockDim.x + threadIdx.x;   // NN*64 threads
    if (gid >= NN * 64) return;
    int row = gid >> 6, cg = gid & 63;
    int col = cg * 8;
    float v[8];
    if (cg < 62) {
        const float4* p = (const float4*)(x + (size_t)row * FIN + col);
        float4 a = p[0], b = p[1];
        v[0] = a.x; v[1] = a.y; v[2] = a.z; v[3] = a.w;
        v[4] = b.x; v[5] = b.y; v[6] = b.z; v[7] = b.w;
    } else {
        #pragma unroll
        for (int j = 0; j < 8; ++j)
            v[j] = (col + j < FIN) ? x[(size_t)row * FIN + col + j] : 0.f;
    }
    uint4 o;
    o.x = (unsigned)f2bu(v[0]) | ((unsigned)f2bu(v[1]) << 16);
    o.y = (unsigned)f2bu(v[2]) | ((unsigned)f2bu(v[3]) << 16);
    o.z = (unsigned)f2bu(v[4]) | ((unsigned)f2bu(v[5]) << 16);
    o.w = (unsigned)f2bu(v[6]) | ((unsigned)f2bu(v[7]) << 16);
    *(uint4*)(xb_u + (size_t)row * 256 + cg * 4) = o;
}

// ---------------- MFMA GEMM: out[M, NT*16] = Ab[M, KB*32] @ W ----------------
// MODE 0: bf16 store only (xp|xn); head computes sigma output in edge order
// MODE 1: v = relu(acc + bias[col]); bf16 store; sl/sr epilogue          (lin0)
// MODE 2: v = relu((1-beta)*bf2f(Ab[row][col]) + beta*acc); bf16 store;
//         optional fp32 store (last layer); sl/sr epilogue
template <int NT, int KB, int MODE>
__global__ __launch_bounds__(256) void mgemm_k(const bf16* __restrict__ Ab,
                                               const bf16* __restrict__ Wt, int M,
                                               const float* __restrict__ bias, float beta,
                                               float* __restrict__ out_f,
                                               bf16* __restrict__ out_b,
                                               const float* __restrict__ alp,
                                               const float* __restrict__ arp,
                                               float* __restrict__ sl,
                                               float* __restrict__ sr,
                                               float* __restrict__ sig_out,
                                               const int* __restrict__ srcA,
                                               const int* __restrict__ dstA) {
    // fused sigma output (MODE 0): edge-order compute from L2-resident sl/sr
    if (MODE == 0) {
        int gid = blockIdx.x * 256 + threadIdx.x;
        int stride = gridDim.x * 256;
        for (int e = gid; e < EP; e += stride) {
            int s, d;
            if (e < NE) { s = srcA[e]; d = dstA[e]; }
            else { s = d = e - NE; }
            float xg = sl[s] + sr[d];
            float lr = (xg > 0.f) ? xg : NEG_SLOPE * xg;
            sig_out[e] = 1.f / (1.f + expf(-lr));
        }
    }
    const int lane = threadIdx.x & 63;
    const int wv = threadIdx.x >> 6;
    const int m0 = blockIdx.x * 64 + wv * 16;
    const int mrow = lane & 15;
    const int quad = lane >> 4;
    int arow = m0 + mrow;
    if (arow >= M) arow = M - 1;
    const bf16* Arow = Ab + (size_t)arow * (KB * 32) + quad * 8;
    const bf16x8* wbase = reinterpret_cast<const bf16x8*>(Wt) + (size_t)lane;

    f32x4 acc[NT];
    #pragma unroll
    for (int t = 0; t < NT; ++t) acc[t] = (f32x4){0.f, 0.f, 0.f, 0.f};

    #pragma unroll
    for (int kb = 0; kb < KB; ++kb) {
        bf16x8 a = *reinterpret_cast<const bf16x8*>(Arow + kb * 32);
        #pragma unroll
        for (int t = 0; t < NT; ++t) {
            bf16x8 b = wbase[(size_t)(t * KB + kb) * 64];
            acc[t] = __builtin_amdgcn_mfma_f32_16x16x32_bf16(a, b, acc[t], 0, 0, 0);
        }
    }

    constexpr int NC = NT * 16;
    #pragma unroll
    for (int t = 0; t < NT; ++t) {
        int col = t * 16 + mrow;
        #pragma unroll
        for (int r = 0; r < 4; ++r) {
            int row = m0 + quad * 4 + r;
            float v = acc[t][r];
            if (MODE == 1) v = fmaxf(v + bias[col], 0.f);
            if (MODE == 2) {
                float h = (row < M) ? (float)Ab[(size_t)row * NC + col] : 0.f;
                v = fmaxf((1.f - beta) * h + beta * v, 0.f);
            }
            acc[t][r] = v;
            if (row < M) {
                if (MODE == 2 && out_f != nullptr) out_f[(size_t)row * NC + col] = v;
                out_b[(size_t)row * NC + col] = (bf16)v;
            }
        }
    }
    // sl/sr epilogue: fp32 dot of each produced row with alp/arp (next layer's gate)
    if ((MODE == 1 || MODE == 2) && alp != nullptr) {
        float sa[4] = {0.f, 0.f, 0.f, 0.f}, sb[4] = {0.f, 0.f, 0.f, 0.f};
        #pragma unroll
        for (int t = 0; t < NT; ++t) {
            float av = alp[t * 16 + mrow];
            float bv = arp[t * 16 + mrow];
            #pragma unroll
            for (int r = 0; r < 4; ++r) {
                sa[r] += acc[t][r] * av;
                sb[r] += acc[t][r] * bv;
            }
        }
        #pragma unroll
        for (int r = 0; r < 4; ++r) {
            #pragma unroll
            for (int m = 1; m < 16; m <<= 1) {
                sa[r] += __shfl_xor(sa[r], m);
                sb[r] += __shfl_xor(sb[r], m);
            }
        }
        if (mrow == 0) {
            #pragma unroll
            for (int r = 0; r < 4; ++r) {
                int row = m0 + quad * 4 + r;
                if (row < M) { sl[row] = sa[r]; sr[row] = sb[r]; }
            }
        }
    }
}

// one wave per node: fused gate + aggregate.
// hn = 0.9*(sum ew*s*xp[src] + (sum ew*(1-s))*xn[wid]) + 0.1*x0b[wid] -> bf16
__global__ __launch_bounds__(256) void agg_k(const int* __restrict__ offs,
                                             const int2* __restrict__ csr2,
                                             const float* __restrict__ sl,
                                             const float* __restrict__ sr,
                                             const unsigned* __restrict__ xpnb_u,
                                             const unsigned* __restrict__ x0b_u,
                                             unsigned* __restrict__ hnb_u, int n) {
    int wid = (blockIdx.x * blockDim.x + threadIdx.x) >> 6;  // node
    int lane = threadIdx.x & 63;
    if (wid >= n) return;
    int s0 = offs[wid], s1 = offs[wid + 1];
    float srw = sr[wid];                 // wave-uniform
    const int g = lane >> 4;             // edge slot 0..3
    const int cg = lane & 15;            // column group (8 bf16 cols)
    float acc[8];
    #pragma unroll
    for (int i = 0; i < 8; ++i) acc[i] = 0.f;
    float cnl = 0.f;

    for (int j0 = s0; j0 < s1; j0 += 64) {
        int j = j0 + lane;
        int msrc = 0;
        float mcoef = 0.f;
        if (j < s1) {
            int2 e = csr2[j];
            float ew = __builtin_bit_cast(float, e.y);
            float xg = sl[e.x] + srw;
            float lr = (xg > 0.f) ? xg : NEG_SLOPE * xg;
            float sg = 1.f / (1.f + expf(-lr));
            msrc = e.x;
            mcoef = ew * sg;
            cnl += ew * (1.f - sg);
        }
        int cnt = min(64, s1 - j0);
        for (int t = 0; t < cnt; t += 4) {
            int idx = t + g;
            float coef = __shfl(mcoef, idx);
            int srcn = __shfl(msrc, idx);
            if (coef != 0.f) {           // tail slots (idx>=cnt) have coef==0: skip load
                uint4 v = *(const uint4*)(xpnb_u + (size_t)srcn * 128 + cg * 4);
                acc[0] += coef * bulo(v.x);
                acc[1] += coef * buhi(v.x);
                acc[2] += coef * bulo(v.y);
                acc[3] += coef * buhi(v.y);
                acc[4] += coef * bulo(v.z);
                acc[5] += coef * buhi(v.z);
                acc[6] += coef * bulo(v.w);
                acc[7] += coef * buhi(v.w);
            }
        }
    }
    #pragma unroll
    for (int i = 0; i < 8; ++i) {
        acc[i] += __shfl_xor(acc[i], 16);
        acc[i] += __shfl_xor(acc[i], 32);
    }
    #pragma unroll
    for (int m = 1; m < 64; m <<= 1) cnl += __shfl_xor(cnl, m);
    unsigned un = xpnb_u[(size_t)wid * 128 + 64 + cg * 4 + g];
    unsigned u0 = x0b_u[(size_t)wid * 64 + cg * 4 + g];
    float ox = (1.f - ALPHA) * (acc[g * 2] + cnl * bulo(un)) + ALPHA * bulo(u0);
    float oy = (1.f - ALPHA) * (acc[g * 2 + 1] + cnl * buhi(un)) + ALPHA * buhi(u0);
    hnb_u[(size_t)wid * 64 + cg * 4 + g] = (unsigned)f2bu(ox) | ((unsigned)f2bu(oy) << 16);
}

// logits + log_softmax (fp32 h input)
__global__ __launch_bounds__(256) void logits_k(const float* __restrict__ h,
                                                const float* __restrict__ w,
                                                const float* __restrict__ b,
                                                float* __restrict__ out, int n) {
    __shared__ float ws[C * NCLS];
    __shared__ float bs[NCLS];
    for (int i = threadIdx.x; i < C * NCLS; i += 256) ws[i] = w[i];
    if (threadIdx.x < NCLS) bs[threadIdx.x] = b[threadIdx.x];
    __syncthreads();
    int i = blockIdx.x * blockDim.x + threadIdx.x;
    if (i >= n) return;
    const float4* hr = (const float4*)(h + (size_t)i * C);
    float acc[NCLS];
    #pragma unroll
    for (int c = 0; c < NCLS; ++c) acc[c] = 0.f;
    for (int k4 = 0; k4 < C / 4; ++k4) {
        float4 v = hr[k4];
        int k = k4 * 4;
        #pragma unroll
        for (int c = 0; c < NCLS; ++c) {
            acc[c] += v.x * ws[k * NCLS + c] + v.y * ws[(k + 1) * NCLS + c] +
                      v.z * ws[(k + 2) * NCLS + c] + v.w * ws[(k + 3) * NCLS + c];
        }
    }
    float lg[NCLS], m = -1e30f;
    #pragma unroll
    for (int c = 0; c < NCLS; ++c) { lg[c] = acc[c] + bs[c]; m = fmaxf(m, lg[c]); }
    float sum = 0.f;
    #pragma unroll
    for (int c = 0; c < NCLS; ++c) sum += expf(lg[c] - m);
    float lse = m + logf(sum);
    #pragma unroll
    for (int c = 0; c < NCLS; ++c) out[(size_t)i * NCLS + c] = lg[c] - lse;
}

extern "C" void kernel_launch(void* const* d_in, const int* in_sizes, int n_in,
                              void* d_out, int out_size, void* d_ws, size_t ws_size,
                              hipStream_t stream) {
    (void)in_sizes; (void)n_in; (void)out_size; (void)ws_size;
    const float* x      = (const float*)d_in[0];
    const int*   eidx   = (const int*)d_in[1];
    const float* lin0_w = (const float*)d_in[2];
    const float* lin0_b = (const float*)d_in[3];
    const float* lin1_w = (const float*)d_in[4];
    const float* lin1_b = (const float*)d_in[5];
    const float* lin_w  = (const float*)d_in[6];
    const float* att_l  = (const float*)d_in[7];
    const float* att_r  = (const float*)d_in[8];
    const float* w_p    = (const float*)d_in[9];
    const float* w_n    = (const float*)d_in[10];
    const float* w1     = (const float*)d_in[11];
    float* outp = (float*)d_out;
    float* sig_base = outp + (size_t)NN * NCLS;   // sigmas [L, EP]

    const int* srcA = eidx;
    const int* dstA = eidx + NE;

    // ---------------- workspace carve-up ----------------
    float* f = (float*)d_ws;
    float* hF   = f; f += (size_t)NN * C;        // fp32 h, last layer only
    float* sl   = f; f += NN;
    float* sr   = f; f += NN;
    float* dinv = f; f += NN;
    float* alp  = f; f += NL * C;
    float* arp  = f; f += NL * C;
    f = (float*)(((uintptr_t)f + 15) & ~(uintptr_t)15);
    // bf16 region
    bf16* bp = (bf16*)f;
    bf16* xb    = bp;                               // overlays xpnb..hb (dead after lin0)
    bf16* xpnb  = bp;  bp += (size_t)NN * 2 * C;
    bf16* hnb   = bp;  bp += (size_t)NN * C;
    bf16* hb    = bp;  bp += (size_t)NN * C;
    bf16* x0b   = bp;  bp += (size_t)NN * C;
    bf16* wpnt  = bp;  bp += (size_t)NL * 16 * 4 * 64 * 8;
    bf16* w1t   = bp;  bp += (size_t)NL * 8 * 4 * 64 * 8;
    bf16* lin0t = bp;  bp += (size_t)8 * 16 * 64 * 8;
    int* ip = (int*)bp;
    int* deg     = ip; ip += NN;
    int* offs    = ip; ip += NN + 4;
    int* cursor  = ip; ip += NN;
    int* exoff   = ip; ip += NN;
    int* bsum    = ip; ip += SCB;
    int* boff    = ip; ip += SCB;
    ip = (int*)(((uintptr_t)ip + 7) & ~(uintptr_t)7);
    int2* csr2   = (int2*)ip;

    dim3 B(256);
    int gN   = (NN + 255) / 256;
    int gE   = (NE + 255) / 256;
    int gEP  = (EP + 255) / 256;
    int gM64 = (NN + 63) / 64;
    int gAgg = NN / 4;

    // ---- graph prep ----
    hipMemsetAsync(deg, 0, (size_t)NN * sizeof(int), stream);
    count_deg_k<<<gE, B, 0, stream>>>(dstA, deg, NE);
    scan1_k<<<NSB, SCB, 0, stream>>>(deg, exoff, bsum, dinv, NN);
    scan2_k<<<1, SCB, 0, stream>>>(bsum, boff, NSB);
    scan3_k<<<NSB, SCB, 0, stream>>>(exoff, boff, offs, cursor, NN);
    csr_fill_k<<<gEP, B, 0, stream>>>(srcA, dstA, dinv, cursor, csr2);
    attproj_k<<<NL, C, 0, stream>>>(lin_w, att_l, att_r, alp, arp);

    // ---- weight packs + input conversion ----
    pack_k<<<NL * 96 + 128, 64, 0, stream>>>(w_p, w_n, w1, lin0_w, wpnt, w1t, lin0t);
    conv_x_k<<<(NN * 64 + 255) / 256, B, 0, stream>>>(x, (unsigned*)xb);

    // ---- x0 = relu(x @ lin0_w + b) -> x0b bf16; epilogue: sl/sr for layer 0 ----
    mgemm_k<8, 16, 1><<<gM64, B, 0, stream>>>(xb, lin0t, NN, lin0_b, 0.f,
                                              nullptr, x0b, alp, arp, sl, sr,
                                              nullptr, nullptr, nullptr);

    // ---- layers ----
    const bf16* curb = x0b;
    for (int l = 0; l < NL; ++l) {
        float beta = (float)log(0.5 / (double)(l + 1) + 1.0);
        bool last = (l == NL - 1);
        // xp|xn GEMM; head writes this layer's sigma output (edge order)
        mgemm_k<16, 4, 0><<<gM64, B, 0, stream>>>(curb, wpnt + (size_t)l * 16 * 4 * 64 * 8,
                                                  NN, nullptr, 0.f, nullptr, xpnb,
                                                  nullptr, nullptr, sl, sr,
                                                  sig_base + (size_t)l * EP, srcA, dstA);
        // fused gate + aggregate -> hnb bf16
        agg_k<<<gAgg, B, 0, stream>>>(offs, csr2, sl, sr, (const unsigned*)xpnb,
                                      (const unsigned*)x0b, (unsigned*)hnb, NN);
        // w1 mix GEMM; epilogue: next layer's sl/sr
        mgemm_k<8, 4, 2><<<gM64, B, 0, stream>>>(hnb, w1t + (size_t)l * 8 * 4 * 64 * 8,
                                                 NN, nullptr, beta,
                                                 last ? hF : nullptr, hb,
                                                 last ? nullptr : (alp + (l + 1) * C),
                                                 last ? nullptr : (arp + (l + 1) * C),
                                                 last ? nullptr : sl,
                                                 last ? nullptr : sr,
                                                 nullptr, nullptr, nullptr);
        curb = hb;
    }

    // ---- logits + log_softmax ----
    logits_k<<<gN, B, 0, stream>>>(hF, lin1_w, lin1_b, outp, NN);
}

// Round 7
// 961.542 us; speedup vs baseline: 1.2666x; 1.2666x over previous
//
#include <hip/hip_runtime.h>
#include <math.h>

// Problem constants
constexpr int NN   = 50000;          // nodes
constexpr int NE   = 800000;         // edges (without self loops)
constexpr int EP   = NE + NN;        // edges + self loops = 850000
constexpr int FIN  = 500;
constexpr int C    = 128;
constexpr int NCLS = 7;
constexpr int NL   = 8;
constexpr float ALPHA = 0.1f;
constexpr float NEG_SLOPE = 0.2f;

typedef __bf16 bf16;
typedef __bf16 bf16x8 __attribute__((ext_vector_type(8)));
typedef float  f32x4  __attribute__((ext_vector_type(4)));

__device__ inline unsigned short f2bu(float f) {
    bf16 b = (bf16)f;
    return __builtin_bit_cast(unsigned short, b);
}
__device__ inline float bulo(unsigned u) { return __builtin_bit_cast(float, u << 16); }
__device__ inline float buhi(unsigned u) { return __builtin_bit_cast(float, u & 0xffff0000u); }

// ---------------- graph prep ----------------
__global__ void count_deg_k(const int* __restrict__ dst, int* __restrict__ deg, int e) {
    int i = blockIdx.x * blockDim.x + threadIdx.x;
    if (i < e) atomicAdd(&deg[dst[i]], 1);
}

// ---- 3-pass scan (deg+1 for self loop; also emits dinv) ----
constexpr int SCB = 256;
constexpr int NSB = (NN + SCB - 1) / SCB;      // 196

__global__ __launch_bounds__(SCB) void scan1_k(const int* __restrict__ deg,
                                               int* __restrict__ exoff,
                                               int* __restrict__ bsum,
                                               float* __restrict__ dinv, int n) {
    __shared__ int s[SCB];
    int t = threadIdx.x;
    int i = blockIdx.x * SCB + t;
    int v = (i < n) ? deg[i] + 1 : 0;          // +1: self loop
    if (i < n) dinv[i] = rsqrtf((float)v);
    s[t] = v;
    __syncthreads();
    for (int off = 1; off < SCB; off <<= 1) {
        int u = (t >= off) ? s[t - off] : 0;
        __syncthreads();
        s[t] += u;
        __syncthreads();
    }
    if (i < n) exoff[i] = s[t] - v;
    if (t == SCB - 1) bsum[blockIdx.x] = s[t];
}

__global__ __launch_bounds__(SCB) void scan2_k(const int* __restrict__ bsum,
                                               int* __restrict__ boff, int nb) {
    __shared__ int s[SCB];
    int t = threadIdx.x;
    int v = (t < nb) ? bsum[t] : 0;
    s[t] = v;
    __syncthreads();
    for (int off = 1; off < SCB; off <<= 1) {
        int u = (t >= off) ? s[t - off] : 0;
        __syncthreads();
        s[t] += u;
        __syncthreads();
    }
    if (t < nb) boff[t] = s[t] - v;
}

__global__ __launch_bounds__(SCB) void scan3_k(const int* __restrict__ exoff,
                                               const int* __restrict__ boff,
                                               int* __restrict__ offs,
                                               int* __restrict__ cursor, int n) {
    int i = blockIdx.x * SCB + threadIdx.x;
    if (i < n) {
        int o = exoff[i] + boff[blockIdx.x];
        offs[i] = o;
        cursor[i] = o;
    }
    if (i == 0) offs[n] = EP;
}

// ---------------- fused prep: csr_fill | conv_x | pack | attproj ----------------
constexpr int PREP_A = (EP + 255) / 256;        // 3321  csr_fill blocks
constexpr int PREP_B = NN * 64 / 256;           // 12500 conv_x blocks
constexpr int PREP_C = (NL * 96 + 128) / 4;     // 224   pack blocks (4 units each)
constexpr int PREP_D = NL;                      // 8     attproj blocks

__global__ __launch_bounds__(256) void prep_k(
        const int* __restrict__ srcA, const int* __restrict__ dstA,
        const float* __restrict__ dinv, int* __restrict__ cursor,
        int2* __restrict__ csr2, int* __restrict__ pos_of,
        const float* __restrict__ x, unsigned* __restrict__ xb_u,
        const float* __restrict__ w_p, const float* __restrict__ w_n,
        const float* __restrict__ w1, const float* __restrict__ lin0_w,
        bf16* __restrict__ wpnt, bf16* __restrict__ w1t, bf16* __restrict__ lin0t,
        const float* __restrict__ lin_w, const float* __restrict__ att_l,
        const float* __restrict__ att_r, float* __restrict__ alp,
        float* __restrict__ arp) {
    int b = blockIdx.x;
    if (b < PREP_A) {
        // ---- csr_fill: scatter {src, ew}; pos_of sequential ----
        int e = b * 256 + threadIdx.x;
        if (e < EP) {
            int s, d;
            if (e < NE) { s = srcA[e]; d = dstA[e]; }
            else { s = d = e - NE; }
            float ew = dinv[s] * dinv[d];
            int pos = atomicAdd(&cursor[d], 1);
            csr2[pos] = make_int2(s, __builtin_bit_cast(int, ew));
            pos_of[e] = pos;
        }
    } else if (b < PREP_A + PREP_B) {
        // ---- conv_x: x [N,500] fp32 -> xb [N,512] bf16, 8 cols/thread ----
        int gid = (b - PREP_A) * 256 + threadIdx.x;    // < NN*64 exactly
        int row = gid >> 6, cg = gid & 63;
        int col = cg * 8;
        float v[8];
        if (cg < 62) {
            const float4* p = (const float4*)(x + (size_t)row * FIN + col);
            float4 a = p[0], bb = p[1];
            v[0] = a.x; v[1] = a.y; v[2] = a.z; v[3] = a.w;
            v[4] = bb.x; v[5] = bb.y; v[6] = bb.z; v[7] = bb.w;
        } else {
            #pragma unroll
            for (int j = 0; j < 8; ++j)
                v[j] = (col + j < FIN) ? x[(size_t)row * FIN + col + j] : 0.f;
        }
        uint4 o;
        o.x = (unsigned)f2bu(v[0]) | ((unsigned)f2bu(v[1]) << 16);
        o.y = (unsigned)f2bu(v[2]) | ((unsigned)f2bu(v[3]) << 16);
        o.z = (unsigned)f2bu(v[4]) | ((unsigned)f2bu(v[5]) << 16);
        o.w = (unsigned)f2bu(v[6]) | ((unsigned)f2bu(v[7]) << 16);
        *(uint4*)(xb_u + (size_t)row * 256 + cg * 4) = o;
    } else if (b < PREP_A + PREP_B + PREP_C) {
        // ---- weight packs into MFMA B-fragment layout (4 64-lane units/block) ----
        int u = (b - PREP_A - PREP_B) * 4 + (threadIdx.x >> 6);
        int lane = threadIdx.x & 63;
        if (u < NL * 64) {
            int l = u >> 6, inner = u & 63;
            int nt = inner >> 2, kb = inner & 3;
            const float* W = ((nt < 8) ? w_p : w_n) + (size_t)l * C * C;
            int col = (nt & 7) * 16 + (lane & 15);
            int k0 = kb * 32 + (lane >> 4) * 8;
            bf16* o = wpnt + (((size_t)l * 64 + inner) * 64 + lane) * 8;
            #pragma unroll
            for (int j = 0; j < 8; ++j) o[j] = (bf16)W[(size_t)(k0 + j) * C + col];
        } else if (u < NL * 96) {
            int idx = u - NL * 64;
            int l = idx >> 5, inner = idx & 31;
            int nt = inner >> 2, kb = inner & 3;
            const float* W = w1 + (size_t)l * C * C;
            int col = nt * 16 + (lane & 15);
            int k0 = kb * 32 + (lane >> 4) * 8;
            bf16* o = w1t + (((size_t)l * 32 + inner) * 64 + lane) * 8;
            #pragma unroll
            for (int j = 0; j < 8; ++j) o[j] = (bf16)W[(size_t)(k0 + j) * C + col];
        } else {
            int idx = u - NL * 96;
            int nt = idx >> 4, kb = idx & 15;
            int col = nt * 16 + (lane & 15);
            int k0 = kb * 32 + (lane >> 4) * 8;
            bf16* o = lin0t + (((size_t)(nt * 16 + kb)) * 64 + lane) * 8;
            #pragma unroll
            for (int j = 0; j < 8; ++j) {
                int k = k0 + j;
                o[j] = (bf16)((k < FIN) ? lin0_w[(size_t)k * C + col] : 0.f);
            }
        }
    } else {
        // ---- attproj: alp[l] = lin_w[l] @ att_l[l]; arp likewise ----
        __shared__ float al[C], ar[C];
        int l = b - (PREP_A + PREP_B + PREP_C);
        int k = threadIdx.x;
        if (k < C) { al[k] = att_l[l * C + k]; ar[k] = att_r[l * C + k]; }
        __syncthreads();
        if (k < C) {
            const float* w = lin_w + (size_t)l * C * C + (size_t)k * C;
            float s1 = 0.f, s2 = 0.f;
            #pragma unroll 8
            for (int c = 0; c < C; ++c) { float v = w[c]; s1 += v * al[c]; s2 += v * ar[c]; }
            alp[l * C + k] = s1;
            arp[l * C + k] = s2;
        }
    }
}

// ---------------- MFMA GEMM: out[M, NT*16] = Ab[M, KB*32] @ W ----------------
// MODE 0: bf16 store only (xp|xn)
// MODE 1: v = relu(acc + bias[col]); bf16 store; sl/sr epilogue          (lin0)
// MODE 2: v = relu((1-beta)*bf2f(Ab[row][col]) + beta*acc); bf16 store;
//         optional fp32 store (last layer); sl/sr epilogue; head permutes sigma
template <int NT, int KB, int MODE>
__global__ __launch_bounds__(256) void mgemm_k(const bf16* __restrict__ Ab,
                                               const bf16* __restrict__ Wt, int M,
                                               const float* __restrict__ bias, float beta,
                                               float* __restrict__ out_f,
                                               bf16* __restrict__ out_b,
                                               const float* __restrict__ alp,
                                               const float* __restrict__ arp,
                                               float* __restrict__ sl,
                                               float* __restrict__ sr,
                                               float* __restrict__ sig_out,
                                               const float* __restrict__ sigc,
                                               const int* __restrict__ pos_of) {
    // fused sigma permute (MODE 2): sig_out[e] = sigc[pos_of[e]]
    if (MODE == 2) {
        int gid = blockIdx.x * 256 + threadIdx.x;
        int stride = gridDim.x * 256;
        for (int e = gid; e < EP; e += stride) sig_out[e] = sigc[pos_of[e]];
    }
    const int lane = threadIdx.x & 63;
    const int wv = threadIdx.x >> 6;
    const int m0 = blockIdx.x * 64 + wv * 16;
    const int mrow = lane & 15;
    const int quad = lane >> 4;
    int arow = m0 + mrow;
    if (arow >= M) arow = M - 1;
    const bf16* Arow = Ab + (size_t)arow * (KB * 32) + quad * 8;
    const bf16x8* wbase = reinterpret_cast<const bf16x8*>(Wt) + (size_t)lane;

    f32x4 acc[NT];
    #pragma unroll
    for (int t = 0; t < NT; ++t) acc[t] = (f32x4){0.f, 0.f, 0.f, 0.f};

    #pragma unroll
    for (int kb = 0; kb < KB; ++kb) {
        bf16x8 a = *reinterpret_cast<const bf16x8*>(Arow + kb * 32);
        #pragma unroll
        for (int t = 0; t < NT; ++t) {
            bf16x8 b = wbase[(size_t)(t * KB + kb) * 64];
            acc[t] = __builtin_amdgcn_mfma_f32_16x16x32_bf16(a, b, acc[t], 0, 0, 0);
        }
    }

    constexpr int NC = NT * 16;
    #pragma unroll
    for (int t = 0; t < NT; ++t) {
        int col = t * 16 + mrow;
        #pragma unroll
        for (int r = 0; r < 4; ++r) {
            int row = m0 + quad * 4 + r;
            float v = acc[t][r];
            if (MODE == 1) v = fmaxf(v + bias[col], 0.f);
            if (MODE == 2) {
                float h = (row < M) ? (float)Ab[(size_t)row * NC + col] : 0.f;
                v = fmaxf((1.f - beta) * h + beta * v, 0.f);
            }
            acc[t][r] = v;
            if (row < M) {
                if (MODE == 2 && out_f != nullptr) out_f[(size_t)row * NC + col] = v;
                out_b[(size_t)row * NC + col] = (bf16)v;
            }
        }
    }
    // sl/sr epilogue: fp32 dot of each produced row with alp/arp (next layer's gate)
    if ((MODE == 1 || MODE == 2) && alp != nullptr) {
        float sa[4] = {0.f, 0.f, 0.f, 0.f}, sb[4] = {0.f, 0.f, 0.f, 0.f};
        #pragma unroll
        for (int t = 0; t < NT; ++t) {
            float av = alp[t * 16 + mrow];
            float bv = arp[t * 16 + mrow];
            #pragma unroll
            for (int r = 0; r < 4; ++r) {
                sa[r] += acc[t][r] * av;
                sb[r] += acc[t][r] * bv;
            }
        }
        #pragma unroll
        for (int r = 0; r < 4; ++r) {
            #pragma unroll
            for (int m = 1; m < 16; m <<= 1) {
                sa[r] += __shfl_xor(sa[r], m);
                sb[r] += __shfl_xor(sb[r], m);
            }
        }
        if (mrow == 0) {
            #pragma unroll
            for (int r = 0; r < 4; ++r) {
                int row = m0 + quad * 4 + r;
                if (row < M) { sl[row] = sa[r]; sr[row] = sb[r]; }
            }
        }
    }
}

// one wave per node: fused gate + aggregate (R5 structure: unconditional gathers).
// hn = 0.9*(sum ew*s*xp[src] + (sum ew*(1-s))*xn[wid]) + 0.1*x0b[wid] -> bf16
// sigma written in CSR order (sigc); permuted to edge order by next w1-GEMM head.
__global__ __launch_bounds__(256) void agg_k(const int* __restrict__ offs,
                                             const int2* __restrict__ csr2,
                                             const float* __restrict__ sl,
                                             const float* __restrict__ sr,
                                             const unsigned* __restrict__ xpnb_u,
                                             const unsigned* __restrict__ x0b_u,
                                             float* __restrict__ sigc,
                                             unsigned* __restrict__ hnb_u, int n) {
    int wid = (blockIdx.x * blockDim.x + threadIdx.x) >> 6;  // node
    int lane = threadIdx.x & 63;
    if (wid >= n) return;
    int s0 = offs[wid], s1 = offs[wid + 1];
    float srw = sr[wid];                 // wave-uniform
    const int g = lane >> 4;             // edge slot 0..3
    const int cg = lane & 15;            // column group (8 bf16 cols)
    float acc[8];
    #pragma unroll
    for (int i = 0; i < 8; ++i) acc[i] = 0.f;
    float cnl = 0.f;

    for (int j0 = s0; j0 < s1; j0 += 64) {
        int j = j0 + lane;
        int msrc = 0;
        float mcoef = 0.f;
        if (j < s1) {
            int2 e = csr2[j];
            float ew = __builtin_bit_cast(float, e.y);
            float xg = sl[e.x] + srw;
            float lr = (xg > 0.f) ? xg : NEG_SLOPE * xg;
            float sg = 1.f / (1.f + expf(-lr));
            sigc[j] = sg;
            msrc = e.x;
            mcoef = ew * sg;
            cnl += ew * (1.f - sg);
        }
        int cnt = min(64, s1 - j0);
        for (int t = 0; t < cnt; t += 4) {
            int idx = t + g;
            float coef = __shfl(mcoef, idx);       // 0 for tail slots
            int srcn = __shfl(msrc, idx);
            uint4 v = *(const uint4*)(xpnb_u + (size_t)srcn * 128 + cg * 4);
            acc[0] += coef * bulo(v.x);
            acc[1] += coef * buhi(v.x);
            acc[2] += coef * bulo(v.y);
            acc[3] += coef * buhi(v.y);
            acc[4] += coef * bulo(v.z);
            acc[5] += coef * buhi(v.z);
            acc[6] += coef * bulo(v.w);
            acc[7] += coef * buhi(v.w);
        }
    }
    #pragma unroll
    for (int i = 0; i < 8; ++i) {
        acc[i] += __shfl_xor(acc[i], 16);
        acc[i] += __shfl_xor(acc[i], 32);
    }
    #pragma unroll
    for (int m = 1; m < 64; m <<= 1) cnl += __shfl_xor(cnl, m);
    unsigned un = xpnb_u[(size_t)wid * 128 + 64 + cg * 4 + g];
    unsigned u0 = x0b_u[(size_t)wid * 64 + cg * 4 + g];
    float ox = (1.f - ALPHA) * (acc[g * 2] + cnl * bulo(un)) + ALPHA * bulo(u0);
    float oy = (1.f - ALPHA) * (acc[g * 2 + 1] + cnl * buhi(un)) + ALPHA * buhi(u0);
    hnb_u[(size_t)wid * 64 + cg * 4 + g] = (unsigned)f2bu(ox) | ((unsigned)f2bu(oy) << 16);
}

// logits + log_softmax (fp32 h input)
__global__ __launch_bounds__(256) void logits_k(const float* __restrict__ h,
                                                const float* __restrict__ w,
                                                const float* __restrict__ b,
                                                float* __restrict__ out, int n) {
    __shared__ float ws[C * NCLS];
    __shared__ float bs[NCLS];
    for (int i = threadIdx.x; i < C * NCLS; i += 256) ws[i] = w[i];
    if (threadIdx.x < NCLS) bs[threadIdx.x] = b[threadIdx.x];
    __syncthreads();
    int i = blockIdx.x * blockDim.x + threadIdx.x;
    if (i >= n) return;
    const float4* hr = (const float4*)(h + (size_t)i * C);
    float acc[NCLS];
    #pragma unroll
    for (int c = 0; c < NCLS; ++c) acc[c] = 0.f;
    for (int k4 = 0; k4 < C / 4; ++k4) {
        float4 v = hr[k4];
        int k = k4 * 4;
        #pragma unroll
        for (int c = 0; c < NCLS; ++c) {
            acc[c] += v.x * ws[k * NCLS + c] + v.y * ws[(k + 1) * NCLS + c] +
                      v.z * ws[(k + 2) * NCLS + c] + v.w * ws[(k + 3) * NCLS + c];
        }
    }
    float lg[NCLS], m = -1e30f;
    #pragma unroll
    for (int c = 0; c < NCLS; ++c) { lg[c] = acc[c] + bs[c]; m = fmaxf(m, lg[c]); }
    float sum = 0.f;
    #pragma unroll
    for (int c = 0; c < NCLS; ++c) sum += expf(lg[c] - m);
    float lse = m + logf(sum);
    #pragma unroll
    for (int c = 0; c < NCLS; ++c) out[(size_t)i * NCLS + c] = lg[c] - lse;
}

extern "C" void kernel_launch(void* const* d_in, const int* in_sizes, int n_in,
                              void* d_out, int out_size, void* d_ws, size_t ws_size,
                              hipStream_t stream) {
    (void)in_sizes; (void)n_in; (void)out_size; (void)ws_size;
    const float* x      = (const float*)d_in[0];
    const int*   eidx   = (const int*)d_in[1];
    const float* lin0_w = (const float*)d_in[2];
    const float* lin0_b = (const float*)d_in[3];
    const float* lin1_w = (const float*)d_in[4];
    const float* lin1_b = (const float*)d_in[5];
    const float* lin_w  = (const float*)d_in[6];
    const float* att_l  = (const float*)d_in[7];
    const float* att_r  = (const float*)d_in[8];
    const float* w_p    = (const float*)d_in[9];
    const float* w_n    = (const float*)d_in[10];
    const float* w1     = (const float*)d_in[11];
    float* outp = (float*)d_out;
    float* sig_base = outp + (size_t)NN * NCLS;   // sigmas [L, EP]

    const int* srcA = eidx;
    const int* dstA = eidx + NE;

    // ---------------- workspace carve-up ----------------
    float* f = (float*)d_ws;
    float* hF   = f; f += (size_t)NN * C;        // fp32 h, last layer only
    float* sl   = f; f += NN;
    float* sr   = f; f += NN;
    float* sigc = f; f += EP;                    // sigma in CSR order
    float* dinv = f; f += NN;
    float* alp  = f; f += NL * C;
    float* arp  = f; f += NL * C;
    f = (float*)(((uintptr_t)f + 15) & ~(uintptr_t)15);
    // bf16 region
    bf16* bp = (bf16*)f;
    bf16* xb    = bp;                               // overlays xpnb..hb (dead after lin0)
    bf16* xpnb  = bp;  bp += (size_t)NN * 2 * C;
    bf16* hnb   = bp;  bp += (size_t)NN * C;
    bf16* hb    = bp;  bp += (size_t)NN * C;
    bf16* x0b   = bp;  bp += (size_t)NN * C;
    bf16* wpnt  = bp;  bp += (size_t)NL * 16 * 4 * 64 * 8;
    bf16* w1t   = bp;  bp += (size_t)NL * 8 * 4 * 64 * 8;
    bf16* lin0t = bp;  bp += (size_t)8 * 16 * 64 * 8;
    int* ip = (int*)bp;
    int* deg     = ip; ip += NN;
    int* offs    = ip; ip += NN + 4;
    int* cursor  = ip; ip += NN;
    int* exoff   = ip; ip += NN;
    int* bsum    = ip; ip += SCB;
    int* boff    = ip; ip += SCB;
    int* pos_of  = ip; ip += EP;
    ip = (int*)(((uintptr_t)ip + 7) & ~(uintptr_t)7);
    int2* csr2   = (int2*)ip;

    dim3 B(256);
    int gN   = (NN + 255) / 256;
    int gE   = (NE + 255) / 256;
    int gM64 = (NN + 63) / 64;
    int gAgg = NN / 4;

    // ---- graph prep ----
    hipMemsetAsync(deg, 0, (size_t)NN * sizeof(int), stream);
    count_deg_k<<<gE, B, 0, stream>>>(dstA, deg, NE);
    scan1_k<<<NSB, SCB, 0, stream>>>(deg, exoff, bsum, dinv, NN);
    scan2_k<<<1, SCB, 0, stream>>>(bsum, boff, NSB);
    scan3_k<<<NSB, SCB, 0, stream>>>(exoff, boff, offs, cursor, NN);

    // ---- fused prep: csr scatter | x conversion | weight packs | attproj ----
    prep_k<<<PREP_A + PREP_B + PREP_C + PREP_D, B, 0, stream>>>(
        srcA, dstA, dinv, cursor, csr2, pos_of, x, (unsigned*)xb,
        w_p, w_n, w1, lin0_w, wpnt, w1t, lin0t, lin_w, att_l, att_r, alp, arp);

    // ---- x0 = relu(x @ lin0_w + b) -> x0b bf16; epilogue: sl/sr for layer 0 ----
    mgemm_k<8, 16, 1><<<gM64, B, 0, stream>>>(xb, lin0t, NN, lin0_b, 0.f,
                                              nullptr, x0b, alp, arp, sl, sr,
                                              nullptr, nullptr, nullptr);

    // ---- layers ----
    const bf16* curb = x0b;
    for (int l = 0; l < NL; ++l) {
        float beta = (float)log(0.5 / (double)(l + 1) + 1.0);
        bool last = (l == NL - 1);
        // xp|xn GEMM (bf16 -> bf16)
        mgemm_k<16, 4, 0><<<gM64, B, 0, stream>>>(curb, wpnt + (size_t)l * 16 * 4 * 64 * 8,
                                                  NN, nullptr, 0.f, nullptr, xpnb,
                                                  nullptr, nullptr, nullptr, nullptr,
                                                  nullptr, nullptr, nullptr);
        // fused gate + aggregate -> hnb bf16, sigc (CSR order)
        agg_k<<<gAgg, B, 0, stream>>>(offs, csr2, sl, sr, (const unsigned*)xpnb,
                                      (const unsigned*)x0b, sigc, (unsigned*)hnb, NN);
        // w1 mix GEMM; head permutes sigma to edge order; epilogue: next sl/sr
        mgemm_k<8, 4, 2><<<gM64, B, 0, stream>>>(hnb, w1t + (size_t)l * 8 * 4 * 64 * 8,
                                                 NN, nullptr, beta,
                                                 last ? hF : nullptr, hb,
                                                 last ? nullptr : (alp + (l + 1) * C),
                                                 last ? nullptr : (arp + (l + 1) * C),
                                                 last ? nullptr : sl,
                                                 last ? nullptr : sr,
                                                 sig_base + (size_t)l * EP, sigc, pos_of);
        curb = hb;
    }

    // ---- logits + log_softmax ----
    logits_k<<<gN, B, 0, stream>>>(hF, lin1_w, lin1_b, outp, NN);
}